// Round 4
// baseline (80.007 us; speedup 1.0000x reference)
//
#include <hip/hip_runtime.h>

#define BB 8
#define LL 2048

typedef float f32x4 __attribute__((ext_vector_type(4)));

static __device__ __forceinline__ f32x4 ffma(f32x4 a, f32x4 b, f32x4 c) {
  return __builtin_elementwise_fma(a, b, c);
}
static __device__ __forceinline__ float hsum(f32x4 x) {
  return (x.x + x.y) + (x.z + x.w);
}

// ws layout (floats): pref[BB*NCH*8192] | kap[BB*LL] | nu[BB*LL] | dT[BB*NCH]

// K1: per-chunk partial sums of v k^T and k k^T, plus per-token kappa/nu.
// 2-token unrolled; all loads of a pair issued up-front.
template<int CC_>
__global__ __launch_bounds__(256) void k1_partial(const float* __restrict__ k,
                                                  const float* __restrict__ v,
                                                  float* __restrict__ pref_all,
                                                  float* __restrict__ kap,
                                                  float* __restrict__ nu) {
  constexpr int NCH_ = LL / CC_;
  int s = blockIdx.x / NCH_, c = blockIdx.x % NCH_;
  int tid = threadIdx.x;
  int lane = tid & 63, w = tid >> 6;
  int j0 = __builtin_amdgcn_readfirstlane(w * 16);
  int tok0 = s * LL + c * CC_;
  const float* kb = k + (size_t)tok0 * 64;
  const float* vb = v + (size_t)tok0 * 64;
  f32x4 accA[4] = {}, accK[4] = {};
  for (int t = 0; t < CC_; t += 2) {
    float vl0 = vb[t * 64 + lane], vl1 = vb[(t + 1) * 64 + lane];
    float kl0 = kb[t * 64 + lane], kl1 = kb[(t + 1) * 64 + lane];
    f32x4 s0[4], s1[4];
    #pragma unroll
    for (int e = 0; e < 4; ++e) {
      s0[e] = *(const f32x4*)(kb + t * 64 + j0 + 4 * e);
      s1[e] = *(const f32x4*)(kb + (t + 1) * 64 + j0 + 4 * e);
    }
    f32x4 v04 = {vl0, vl0, vl0, vl0}, k04 = {kl0, kl0, kl0, kl0};
    f32x4 v14 = {vl1, vl1, vl1, vl1}, k14 = {kl1, kl1, kl1, kl1};
    #pragma unroll
    for (int e = 0; e < 4; ++e) {
      accA[e] = ffma(v04, s0[e], accA[e]);
      accK[e] = ffma(k04, s0[e], accK[e]);
      accA[e] = ffma(v14, s1[e], accA[e]);
      accK[e] = ffma(k14, s1[e], accK[e]);
    }
  }
  float* dst = pref_all + (size_t)(s * NCH_ + c) * 8192;
  #pragma unroll
  for (int e = 0; e < 4; ++e) {
    *(f32x4*)(dst + lane * 64 + j0 + 4 * e) = accA[e];
    *(f32x4*)(dst + 4096 + lane * 64 + j0 + 4 * e) = accK[e];
  }
  // kappa/nu: wave w handles tokens w, w+4, ... (rows are L1-warm)
  for (int t = w; t < CC_; t += 4) {
    float kl = kb[t * 64 + lane];
    float vl = vb[t * 64 + lane];
    float pk = kl * kl, pv = vl * vl;
    #pragma unroll
    for (int m = 1; m < 64; m <<= 1) {
      pk += __shfl_xor(pk, m, 64);
      pv += __shfl_xor(pv, m, 64);
    }
    if (lane == 0) {
      kap[tok0 + t] = pk;
      nu[tok0 + t] = pv;
    }
  }
}

// K2: in-place exclusive prefix over chunks; 16-deep batches with next-batch prefetch
template<int NCH_>
__global__ __launch_bounds__(256) void k2_prefix(float* __restrict__ pref_all) {
  int gid = blockIdx.x * 256 + threadIdx.x;   // [0, BB*8192)
  int s = gid >> 13, e = gid & 8191;
  float* base = pref_all + (size_t)s * NCH_ * 8192 + e;
  constexpr int BT = (NCH_ >= 16) ? 16 : NCH_;
  float x[BT];
  #pragma unroll
  for (int u = 0; u < BT; ++u) x[u] = base[(size_t)u * 8192];
  float acc = 0.f;
  for (int cb = 0; cb < NCH_; cb += BT) {
    float y[BT];
    if (cb + BT < NCH_) {
      #pragma unroll
      for (int u = 0; u < BT; ++u) y[u] = base[(size_t)(cb + BT + u) * 8192];
    }
    #pragma unroll
    for (int u = 0; u < BT; ++u) {
      float t = x[u];
      base[(size_t)(cb + u) * 8192] = acc;
      acc += t;
    }
    #pragma unroll
    for (int u = 0; u < BT; ++u) x[u] = y[u];
  }
}

// K3: rank-2 paired sequential scan over one CC_-token chunk. One wave; lane i
// owns row i of A (sum v k^T) and K (sum k k^T). Seedless (emits per-chunk dT).
// Pair algebra: m=k1.k2, u2=S_K k2, w2=S_A k2, s2=b1.k2:
//   b2 = u2 + m k1; a2 = w2 + m v1; d2 = S_A u2 + m a1 + v1 (s2 + m kap1)
template<int CC_>
__global__ __launch_bounds__(64, 1) void k3_scan(const float* __restrict__ k,
                                                 const float* __restrict__ v,
                                                 const float* __restrict__ pref_all,
                                                 const float* __restrict__ kap_all,
                                                 const float* __restrict__ nu_all,
                                                 float* __restrict__ dT,
                                                 float* __restrict__ out) {
  constexpr int NCH_ = LL / CC_;
  int s = blockIdx.x / NCH_, c = blockIdx.x % NCH_;
  int lane = threadIdx.x;
  __shared__ float kpair[2][128];   // double-buffered pair of k rows
  __shared__ float bc[128];         // broadcast of b1 | u2
  const float* pref = pref_all + (size_t)(s * NCH_ + c) * 8192;
  f32x4 SA[16], SK[16];
  #pragma unroll
  for (int j = 0; j < 16; ++j) SA[j] = *(const f32x4*)(pref + lane * 64 + 4 * j);
  #pragma unroll
  for (int j = 0; j < 16; ++j) SK[j] = *(const f32x4*)(pref + 4096 + lane * 64 + 4 * j);
  f32x4 f4 = {};
  #pragma unroll
  for (int j = 0; j < 16; ++j) f4 = ffma(SA[j], SA[j], f4);
  float pF = hsum(f4);              // per-lane ||A0 row||^2 (sums to F0)
  float m0 = (lane == 0) ? 1.f : 0.f;
  float pT = 0.f;
  int tok0 = s * LL + c * CC_;
  const float* kb  = k + (size_t)tok0 * 64;
  const float* vb  = v + (size_t)tok0 * 64;
  const float* kap = kap_all + tok0;
  const float* nuv = nu_all  + tok0;
  // stage pair 0
  float klc1 = kb[lane],      klc2 = kb[64 + lane];
  float vlc1 = vb[lane],      vlc2 = vb[64 + lane];
  float ka1 = kap[0], ka2 = kap[1], nv1 = nuv[0], nv2 = nuv[1];
  kpair[0][lane] = klc1;
  kpair[0][64 + lane] = klc2;

  for (int P = 0; P < CC_ / 2; ++P) {
    int buf = P & 1;
    int Pn = (P + 1 < CC_ / 2) ? P + 1 : P;
    // prefetch next pair (global -> reg, consumed next iteration)
    float kn1 = kb[(2 * Pn) * 64 + lane], kn2 = kb[(2 * Pn + 1) * 64 + lane];
    float vn1 = vb[(2 * Pn) * 64 + lane], vn2 = vb[(2 * Pn + 1) * 64 + lane];
    float kan1 = kap[2 * Pn], kan2 = kap[2 * Pn + 1];
    float nvn1 = nuv[2 * Pn], nvn2 = nuv[2 * Pn + 1];
    // m = k1.k2 butterfly (long slack before first use)
    float m_all = klc1 * klc2;
    #pragma unroll
    for (int mm = 1; mm < 64; mm <<= 1) m_all += __shfl_xor(m_all, mm, 64);
    // broadcast rows of the pair
    f32x4 sk1[16], sk2[16];
    #pragma unroll
    for (int j = 0; j < 16; ++j) {
      sk1[j] = *(const f32x4*)&kpair[buf][4 * j];
      sk2[j] = *(const f32x4*)&kpair[buf][64 + 4 * j];
    }
    // round 1: four independent matvecs from S
    f32x4 B1 = {}, U2 = {}, A1 = {}, W2 = {};
    #pragma unroll
    for (int j = 0; j < 16; ++j) {
      B1 = ffma(SK[j], sk1[j], B1);
      U2 = ffma(SK[j], sk2[j], U2);
      A1 = ffma(SA[j], sk1[j], A1);
      W2 = ffma(SA[j], sk2[j], W2);
    }
    float b1 = hsum(B1), u2 = hsum(U2), a1 = hsum(A1), w2 = hsum(W2);
    bc[lane] = b1;
    bc[64 + lane] = u2;
    // s2 = b1.k2 butterfly (slack over K update + round 2)
    float s2 = klc2 * b1;
    #pragma unroll
    for (int mm = 1; mm < 64; mm <<= 1) s2 += __shfl_xor(s2, mm, 64);
    // K rank-2 update (covers bc write->read latency)
    f32x4 k14 = {klc1, klc1, klc1, klc1}, k24 = {klc2, klc2, klc2, klc2};
    #pragma unroll
    for (int j = 0; j < 16; ++j) SK[j] = ffma(k14, sk1[j], ffma(k24, sk2[j], SK[j]));
    // stage next pair (write-late, other buffer)
    kpair[buf ^ 1][lane] = kn1;
    kpair[buf ^ 1][64 + lane] = kn2;
    // round 2: two matvecs on broadcast b1,u2 (A pre-update)
    f32x4 E1 = {}, E2 = {};
    #pragma unroll
    for (int j = 0; j < 16; ++j) {
      E1 = ffma(SA[j], *(const f32x4*)&bc[4 * j], E1);
      E2 = ffma(SA[j], *(const f32x4*)&bc[64 + 4 * j], E2);
    }
    float d1 = hsum(E1);
    float d2 = hsum(E2) + m_all * a1 + vlc1 * fmaf(m_all, ka1, s2);
    // A rank-2 update
    f32x4 v14 = {vlc1, vlc1, vlc1, vlc1}, v24 = {vlc2, vlc2, vlc2, vlc2};
    #pragma unroll
    for (int j = 0; j < 16; ++j) SA[j] = ffma(v14, sk1[j], ffma(v24, sk2[j], SA[j]));
    float b2 = fmaf(m_all, klc1, u2);
    float a2 = fmaf(m_all, vlc1, w2);
    // epilogue token p
    float r1 = vlc1 * a1;
    pF = fmaf(2.f, r1, pF);
    pF = fmaf(m0, ka1 * nv1, pF);
    float r2 = fmaf(2.f * vlc1, d1, a1 * a1);
    r2 = fmaf(2.f * ka1, r1, r2);
    r2 = fmaf(nv1 * klc1, b1, r2);
    r2 = fmaf(m0, ka1 * ka1 * nv1, r2);
    pT += r2;
    float invp = 1.0f / (float)(c * CC_ + 2 * P + 1);
    float op = invp * invp * fmaf(0.5f * invp, pT, -pF);
    // epilogue token q
    float r1q = vlc2 * a2;
    pF = fmaf(2.f, r1q, pF);
    pF = fmaf(m0, ka2 * nv2, pF);
    float r2q = fmaf(2.f * vlc2, d2, a2 * a2);
    r2q = fmaf(2.f * ka2, r1q, r2q);
    r2q = fmaf(nv2 * klc2, b2, r2q);
    r2q = fmaf(m0, ka2 * ka2 * nv2, r2q);
    pT += r2q;
    float invq = 1.0f / (float)(c * CC_ + 2 * P + 2);
    float oq = invq * invq * fmaf(0.5f * invq, pT, -pF);
    // dual butterfly reduce + store
    #pragma unroll
    for (int mm = 1; mm < 64; mm <<= 1) {
      op += __shfl_xor(op, mm, 64);
      oq += __shfl_xor(oq, mm, 64);
    }
    if (lane == 0) {
      out[tok0 + 2 * P]     = op;
      out[tok0 + 2 * P + 1] = oq;
    }
    // rotate prefetched pair
    klc1 = kn1; klc2 = kn2; vlc1 = vn1; vlc2 = vn2;
    ka1 = kan1; ka2 = kan2; nv1 = nvn1; nv2 = nvn2;
  }
  // chunk trace increment
  #pragma unroll
  for (int mm = 1; mm < 64; mm <<= 1) pT += __shfl_xor(pT, mm, 64);
  if (lane == 0) dT[s * NCH_ + c] = pT;
}

// K4: per-stream: exclusive chunk-prefix of dT -> T0; inclusive nu-prefix ->
// s_tau; out[t] += 0.5*s_tau/tau + 0.5*T0/tau^3.
template<int CC_>
__global__ __launch_bounds__(256) void k4_fix(const float* __restrict__ dT,
                                              const float* __restrict__ nu,
                                              float* __restrict__ out) {
  constexpr int NCH_ = LL / CC_;
  int s = blockIdx.x;
  int tid = threadIdx.x, lane = tid & 63, w = tid >> 6;
  __shared__ float T0s[NCH_];
  __shared__ float wsum[4];
  if (w == 0) {
    constexpr int PER = (NCH_ >= 64) ? NCH_ / 64 : 1;
    float loc[PER];
    float tot = 0.f;
    #pragma unroll
    for (int u = 0; u < PER; ++u) {
      int c = lane * PER + u;
      loc[u] = (c < NCH_) ? dT[s * NCH_ + c] : 0.f;
      tot += loc[u];
    }
    float incl = tot;
    #pragma unroll
    for (int off = 1; off < 64; off <<= 1) {
      float n = __shfl_up(incl, off, 64);
      if (lane >= off) incl += n;
    }
    float run = incl - tot;
    #pragma unroll
    for (int u = 0; u < PER; ++u) {
      int c = lane * PER + u;
      if (c < NCH_) T0s[c] = run;
      run += loc[u];
    }
  }
  __syncthreads();
  const float* nus = nu + s * LL;
  float p[8];
  {
    float run = 0.f;
    #pragma unroll
    for (int u = 0; u < 8; ++u) {
      run += nus[tid * 8 + u];
      p[u] = run;
    }
  }
  float tot = p[7];
  float incl = tot;
  #pragma unroll
  for (int off = 1; off < 64; off <<= 1) {
    float n = __shfl_up(incl, off, 64);
    if (lane >= off) incl += n;
  }
  if (lane == 63) wsum[w] = incl;
  __syncthreads();
  float wbase = 0.f;
  for (int i = 0; i < w; ++i) wbase += wsum[i];
  float base = wbase + incl - tot;
  float* os = out + s * LL;
  #pragma unroll
  for (int u = 0; u < 8; ++u) {
    int t = tid * 8 + u;
    float tau = (float)(t + 1);
    float inv = 1.0f / tau;
    float sincl = base + p[u];
    float t0 = T0s[t / CC_];
    float add = fmaf(0.5f * inv, sincl, 0.5f * inv * inv * inv * t0);
    os[t] += add;
  }
}

template<int CC_>
static void launch_all(const float* k, const float* v, float* ws, float* out,
                       hipStream_t stream) {
  constexpr int NCH_ = LL / CC_;
  float* pref = ws;
  float* kap = ws + (size_t)BB * NCH_ * 8192;
  float* nu  = kap + BB * LL;
  float* dT  = nu + BB * LL;
  hipLaunchKernelGGL(k1_partial<CC_>, dim3(BB * NCH_), dim3(256), 0, stream, k, v, pref, kap, nu);
  hipLaunchKernelGGL(k2_prefix<NCH_>, dim3(BB * 8192 / 256), dim3(256), 0, stream, pref);
  hipLaunchKernelGGL(k3_scan<CC_>, dim3(BB * NCH_), dim3(64), 0, stream, k, v, pref, kap, nu, dT, out);
  hipLaunchKernelGGL(k4_fix<CC_>, dim3(BB), dim3(256), 0, stream, dT, nu, out);
}

extern "C" void kernel_launch(void* const* d_in, const int* in_sizes, int n_in,
                              void* d_out, int out_size, void* d_ws, size_t ws_size,
                              hipStream_t stream) {
  const float* k = (const float*)d_in[1];
  const float* v = (const float*)d_in[2];
  float* out = (float*)d_out;
  float* ws = (float*)d_ws;
  auto need = [](int cc) {
    size_t nch = LL / cc;
    return ((size_t)BB * nch * 8192 + 2ull * BB * LL + (size_t)BB * nch) * 4;
  };
  if (ws_size >= need(32))      launch_all<32>(k, v, ws, out, stream);
  else                          launch_all<64>(k, v, ws, out, stream);
}

// Round 5
// 58.167 us; speedup vs baseline: 1.3755x; 1.3755x over previous
//
#include <hip/hip_runtime.h>

#define BB 8
#define LL 2048
#define CC 64
#define NCH 32

typedef float f32x2 __attribute__((ext_vector_type(2)));
typedef float f32x4 __attribute__((ext_vector_type(4)));

static __device__ __forceinline__ f32x4 ffma4(f32x4 a, f32x4 b, f32x4 c) {
  return __builtin_elementwise_fma(a, b, c);
}
static __device__ __forceinline__ f32x4 bc4(float x) { return (f32x4){x, x, x, x}; }

// ws layout (floats): pref[BB*NCH*8192] | kap[BB*LL] | nu[BB*LL] | u[BB*LL] | w[BB*LL]

// K1: per-chunk partial sums of v k^T and k k^T, plus per-token kappa/nu.
__global__ __launch_bounds__(256) void k1_partial(const float* __restrict__ k,
                                                  const float* __restrict__ v,
                                                  float* __restrict__ pref_all,
                                                  float* __restrict__ kap,
                                                  float* __restrict__ nu) {
  int s = blockIdx.x / NCH, c = blockIdx.x % NCH;
  int tid = threadIdx.x;
  int lane = tid & 63, w = tid >> 6;
  int j0 = __builtin_amdgcn_readfirstlane(w * 16);
  int tok0 = s * LL + c * CC;
  const float* kb = k + (size_t)tok0 * 64;
  const float* vb = v + (size_t)tok0 * 64;
  f32x4 accA[4] = {}, accK[4] = {};
  for (int t = 0; t < CC; t += 2) {
    float vl0 = vb[t * 64 + lane], vl1 = vb[(t + 1) * 64 + lane];
    float kl0 = kb[t * 64 + lane], kl1 = kb[(t + 1) * 64 + lane];
    f32x4 s0[4], s1[4];
    #pragma unroll
    for (int e = 0; e < 4; ++e) {
      s0[e] = *(const f32x4*)(kb + t * 64 + j0 + 4 * e);
      s1[e] = *(const f32x4*)(kb + (t + 1) * 64 + j0 + 4 * e);
    }
    #pragma unroll
    for (int e = 0; e < 4; ++e) {
      accA[e] = ffma4(bc4(vl0), s0[e], accA[e]);
      accK[e] = ffma4(bc4(kl0), s0[e], accK[e]);
      accA[e] = ffma4(bc4(vl1), s1[e], accA[e]);
      accK[e] = ffma4(bc4(kl1), s1[e], accK[e]);
    }
  }
  float* dst = pref_all + (size_t)(s * NCH + c) * 8192;
  #pragma unroll
  for (int e = 0; e < 4; ++e) {
    *(f32x4*)(dst + lane * 64 + j0 + 4 * e) = accA[e];
    *(f32x4*)(dst + 4096 + lane * 64 + j0 + 4 * e) = accK[e];
  }
  for (int t = w; t < CC; t += 4) {
    float kl = kb[t * 64 + lane];
    float vl = vb[t * 64 + lane];
    float pk = kl * kl, pv = vl * vl;
    #pragma unroll
    for (int m = 1; m < 64; m <<= 1) {
      pk += __shfl_xor(pk, m, 64);
      pv += __shfl_xor(pv, m, 64);
    }
    if (lane == 0) {
      kap[tok0 + t] = pk;
      nu[tok0 + t] = pv;
    }
  }
}

// K2: in-place exclusive prefix over chunks; 16-deep batches with prefetch
__global__ __launch_bounds__(256) void k2_prefix(float* __restrict__ pref_all) {
  int gid = blockIdx.x * 256 + threadIdx.x;   // [0, BB*8192)
  int s = gid >> 13, e = gid & 8191;
  float* base = pref_all + (size_t)s * NCH * 8192 + e;
  float x[16];
  #pragma unroll
  for (int u = 0; u < 16; ++u) x[u] = base[(size_t)u * 8192];
  float acc = 0.f;
  for (int cb = 0; cb < NCH; cb += 16) {
    float y[16];
    if (cb + 16 < NCH) {
      #pragma unroll
      for (int u = 0; u < 16; ++u) y[u] = base[(size_t)(cb + 16 + u) * 8192];
    }
    #pragma unroll
    for (int u = 0; u < 16; ++u) {
      float t = x[u];
      base[(size_t)(cb + u) * 8192] = acc;
      acc += t;
    }
    #pragma unroll
    for (int u = 0; u < 16; ++u) x[u] = y[u];
  }
}

// K3: chunk-parallel GEMM formulation. One block (4 waves) per chunk.
// Wave q owns output rows t in [16q,16q+16); lane l owns column l.
// Emits per-token u_t = Delta(Tr(A K A^T)), w_t = Delta(||A||_F^2).
__global__ __launch_bounds__(256, 1) void k3_gemm(const float* __restrict__ k,
                                                  const float* __restrict__ v,
                                                  const float* __restrict__ pref_all,
                                                  const float* __restrict__ kap_all,
                                                  const float* __restrict__ nu_all,
                                                  float* __restrict__ uo,
                                                  float* __restrict__ wo) {
  int s = blockIdx.x >> 5, c = blockIdx.x & 31;
  int tid = threadIdx.x;
  int l = tid & 63, q = tid >> 6;
  int tq = q * 16;
  __shared__ float sKcT[4096];   // Kc^T [m][t], stride 64
  __shared__ float sU1[4352];    // phase1: Vc^T (stride 64); phase3: Brow^T (stride 68)
  __shared__ float sU2[4352];    // phase1: A0^T (stride 64); phase2: masked P^T (stride 68)
  int tok0 = s * LL + c * CC;
  const float* kb = k + (size_t)tok0 * 64;
  const float* vb = v + (size_t)tok0 * 64;
  const float* gA0 = pref_all + (size_t)(s * NCH + c) * 8192;
  const float* gK0 = gA0 + 4096;

  // stage KcT, VcT, A0T (thread: row j=l, col block [tq,tq+16))
  #pragma unroll
  for (int e = 0; e < 4; ++e) {
    f32x4 kk = *(const f32x4*)(kb + l * 64 + tq + 4 * e);
    f32x4 vv = *(const f32x4*)(vb + l * 64 + tq + 4 * e);
    f32x4 aa = *(const f32x4*)(gA0 + l * 64 + tq + 4 * e);
    #pragma unroll
    for (int u2 = 0; u2 < 4; ++u2) {
      int m = tq + 4 * e + u2;
      sKcT[m * 64 + l] = kk[u2];
      sU1[m * 64 + l] = vv[u2];
      sU2[m * 64 + l] = aa[u2];
    }
  }
  __syncthreads();

  f32x4 X4[4] = {}, Y4[4] = {}, M4[4] = {}, G4[4] = {}, N4[4] = {};

  // ---- phase 1: X=Kc A0^T, Y=Kc K0, M=Kc Kc^T, G=Vc A0, N=Vc Vc^T
  {
    f32x4 kcuA[4], vcuA[4], kcuB[4], vcuB[4];
    float a0tA, kctlA, vctlA, a0tB, kctlB, vctlB;
    float a0rE, k0rE, a0rO, k0rO;
    #pragma unroll
    for (int e = 0; e < 4; ++e) {
      kcuA[e] = *(const f32x4*)&sKcT[tq + 4 * e];
      vcuA[e] = *(const f32x4*)&sU1[tq + 4 * e];
    }
    a0tA = sU2[l]; kctlA = sKcT[l]; vctlA = sU1[l];
    a0rE = gA0[l]; k0rE = gK0[l];
    a0rO = gA0[64 + l]; k0rO = gK0[64 + l];
    for (int m = 0; m < 64; m += 2) {
      int m1 = m + 1, m2 = (m + 2) & 63, m3 = (m + 3) & 63;
      #pragma unroll
      for (int e = 0; e < 4; ++e) {
        kcuB[e] = *(const f32x4*)&sKcT[m1 * 64 + tq + 4 * e];
        vcuB[e] = *(const f32x4*)&sU1[m1 * 64 + tq + 4 * e];
      }
      a0tB = sU2[m1 * 64 + l]; kctlB = sKcT[m1 * 64 + l]; vctlB = sU1[m1 * 64 + l];
      #pragma unroll
      for (int e = 0; e < 4; ++e) {
        X4[e] = ffma4(kcuA[e], bc4(a0tA), X4[e]);
        Y4[e] = ffma4(kcuA[e], bc4(k0rE), Y4[e]);
        M4[e] = ffma4(kcuA[e], bc4(kctlA), M4[e]);
        G4[e] = ffma4(vcuA[e], bc4(a0rE), G4[e]);
        N4[e] = ffma4(vcuA[e], bc4(vctlA), N4[e]);
      }
      a0rE = gA0[m2 * 64 + l]; k0rE = gK0[m2 * 64 + l];
      #pragma unroll
      for (int e = 0; e < 4; ++e) {
        kcuA[e] = *(const f32x4*)&sKcT[m2 * 64 + tq + 4 * e];
        vcuA[e] = *(const f32x4*)&sU1[m2 * 64 + tq + 4 * e];
      }
      a0tA = sU2[m2 * 64 + l]; kctlA = sKcT[m2 * 64 + l]; vctlA = sU1[m2 * 64 + l];
      #pragma unroll
      for (int e = 0; e < 4; ++e) {
        X4[e] = ffma4(kcuB[e], bc4(a0tB), X4[e]);
        Y4[e] = ffma4(kcuB[e], bc4(k0rO), Y4[e]);
        M4[e] = ffma4(kcuB[e], bc4(kctlB), M4[e]);
        G4[e] = ffma4(vcuB[e], bc4(a0rO), G4[e]);
        N4[e] = ffma4(vcuB[e], bc4(vctlB), N4[e]);
      }
      a0rO = gA0[m3 * 64 + l]; k0rO = gK0[m3 * 64 + l];
    }
  }
  __syncthreads();   // all phase-1 reads of sU2 (A0T) done
  // masked P^T into sU2 (stride 68): MT[i=l][t] = (i<t) ? M[t,i] : 0
  #pragma unroll
  for (int r = 0; r < 16; ++r) {
    int t = tq + r;
    sU2[l * 68 + t] = (l < t) ? M4[r >> 2][r & 3] : 0.f;
  }
  __syncthreads();

  // ---- phase 2: X += P Vc (Arow), Y += P Kc (Brow)
  {
    f32x4 puA[4], puB[4];
    float vclE, kclE, vclO, kclO;
    #pragma unroll
    for (int e = 0; e < 4; ++e) puA[e] = *(const f32x4*)&sU2[tq + 4 * e];
    vclE = vb[l]; kclE = kb[l];
    vclO = vb[64 + l]; kclO = kb[64 + l];
    for (int i = 0; i < 64; i += 2) {
      int i1 = i + 1, i2 = (i + 2) & 63, i3 = (i + 3) & 63;
      #pragma unroll
      for (int e = 0; e < 4; ++e) puB[e] = *(const f32x4*)&sU2[i1 * 68 + tq + 4 * e];
      #pragma unroll
      for (int e = 0; e < 4; ++e) {
        X4[e] = ffma4(puA[e], bc4(vclE), X4[e]);
        Y4[e] = ffma4(puA[e], bc4(kclE), Y4[e]);
      }
      vclE = vb[i2 * 64 + l]; kclE = kb[i2 * 64 + l];
      #pragma unroll
      for (int e = 0; e < 4; ++e) puA[e] = *(const f32x4*)&sU2[i2 * 68 + tq + 4 * e];
      #pragma unroll
      for (int e = 0; e < 4; ++e) {
        X4[e] = ffma4(puB[e], bc4(vclO), X4[e]);
        Y4[e] = ffma4(puB[e], bc4(kclO), Y4[e]);
      }
      vclO = vb[i3 * 64 + l]; kclO = kb[i3 * 64 + l];
    }
  }
  // BT = Brow^T into sU1 (stride 68); sU1 VcT dead since phase 1
  #pragma unroll
  for (int r = 0; r < 16; ++r) {
    sU1[l * 68 + tq + r] = Y4[r >> 2][r & 3];
  }
  __syncthreads();

  // ---- phase 3: Z[t, i=l] = sum_m Brow[t,m] Kc[i,m] = sum_m BT[m][t] KcT[m][l]
  f32x4 Z4[4] = {};
  {
    f32x4 buA[4], buB[4];
    float ktA, ktB;
    #pragma unroll
    for (int e = 0; e < 4; ++e) buA[e] = *(const f32x4*)&sU1[tq + 4 * e];
    ktA = sKcT[l];
    for (int m = 0; m < 64; m += 2) {
      int m1 = m + 1, m2 = (m + 2) & 63;
      #pragma unroll
      for (int e = 0; e < 4; ++e) buB[e] = *(const f32x4*)&sU1[m1 * 68 + tq + 4 * e];
      ktB = sKcT[m1 * 64 + l];
      #pragma unroll
      for (int e = 0; e < 4; ++e) Z4[e] = ffma4(buA[e], bc4(ktA), Z4[e]);
      #pragma unroll
      for (int e = 0; e < 4; ++e) buA[e] = *(const f32x4*)&sU1[m2 * 68 + tq + 4 * e];
      ktA = sKcT[m2 * 64 + l];
      #pragma unroll
      for (int e = 0; e < 4; ++e) Z4[e] = ffma4(buB[e], bc4(ktB), Z4[e]);
    }
  }

  // ---- epilogue: per-row wave reductions
  // u_t = 2 v.d + ||a||^2 + 2 kap (v.a) + nu (k.b) + kap^2 nu
  // w_t = 2 (v.a) + kap nu
  float usel = 0.f, wsel = 0.f;
  #pragma unroll
  for (int r = 0; r < 16; ++r) {
    int t = tq + r;
    int gt = tok0 + t;
    float ka = kap_all[gt];
    float nv = nu_all[gt];
    float vtl = vb[t * 64 + l];
    float ktl = kb[t * 64 + l];
    float xr = X4[r >> 2][r & 3];   // Arow[t,l]
    float yr = Y4[r >> 2][r & 3];   // Brow[t,l]
    float gr = G4[r >> 2][r & 3];   // (Vc A0)[t,l]
    float nr = N4[r >> 2][r & 3];   // N[t,l]
    float zr = Z4[r >> 2][r & 3];   // Z[t,l]
    float zn = (l < t) ? zr * nr : 0.f;
    float ap = vtl * xr;
    float up = 2.f * (gr * yr + zn) + xr * xr + 2.f * ka * ap + nv * (ktl * yr);
    #pragma unroll
    for (int mm = 1; mm < 64; mm <<= 1) {
      up += __shfl_xor(up, mm, 64);
      ap += __shfl_xor(ap, mm, 64);
    }
    float ut = up + ka * ka * nv;
    float wt = fmaf(2.f, ap, ka * nv);
    bool sel = (l == r);
    usel = sel ? ut : usel;
    wsel = sel ? wt : wsel;
  }
  if (l < 16) {
    uo[tok0 + tq + l] = usel;
    wo[tok0 + tq + l] = wsel;
  }
}

// K4: per-stream inclusive prefixes of u (->T), w (->F), nu (->S); emit out.
__global__ __launch_bounds__(256) void k4_out(const float* __restrict__ u,
                                              const float* __restrict__ w,
                                              const float* __restrict__ nu,
                                              float* __restrict__ out) {
  int s = blockIdx.x;
  int tid = threadIdx.x, l = tid & 63, wv = tid >> 6;
  __shared__ float su[4], sw[4], sn[4];
  const float* us = u + s * LL;
  const float* wsp = w + s * LL;
  const float* ns = nu + s * LL;
  float pu[8], pw[8], pn[8];
  int base = tid * 8;
  {
    float ru = 0, rw = 0, rn = 0;
    #pragma unroll
    for (int e = 0; e < 8; ++e) {
      ru += us[base + e]; pu[e] = ru;
      rw += wsp[base + e]; pw[e] = rw;
      rn += ns[base + e]; pn[e] = rn;
    }
  }
  float tu = pu[7], tw = pw[7], tn = pn[7];
  float iu = tu, iw = tw, in_ = tn;
  #pragma unroll
  for (int off = 1; off < 64; off <<= 1) {
    float a = __shfl_up(iu, off, 64);
    float b = __shfl_up(iw, off, 64);
    float c2 = __shfl_up(in_, off, 64);
    if (l >= off) { iu += a; iw += b; in_ += c2; }
  }
  if (l == 63) { su[wv] = iu; sw[wv] = iw; sn[wv] = in_; }
  __syncthreads();
  float bu = 0, bw = 0, bn = 0;
  for (int i2 = 0; i2 < wv; ++i2) { bu += su[i2]; bw += sw[i2]; bn += sn[i2]; }
  float eu = bu + iu - tu, ew = bw + iw - tw, en = bn + in_ - tn;
  float* os = out + s * LL;
  #pragma unroll
  for (int e = 0; e < 8; ++e) {
    int t = base + e;
    float inv = 1.0f / (float)(t + 1);
    float U = eu + pu[e], W = ew + pw[e], S = en + pn[e];
    os[t] = inv * (0.5f * S + inv * fmaf(0.5f * inv, U, -W));
  }
}

extern "C" void kernel_launch(void* const* d_in, const int* in_sizes, int n_in,
                              void* d_out, int out_size, void* d_ws, size_t ws_size,
                              hipStream_t stream) {
  const float* k = (const float*)d_in[1];
  const float* v = (const float*)d_in[2];
  float* out = (float*)d_out;
  float* ws = (float*)d_ws;
  float* pref = ws;
  float* kap = ws + (size_t)BB * NCH * 8192;
  float* nu  = kap + BB * LL;
  float* uu  = nu + BB * LL;
  float* ww  = uu + BB * LL;
  hipLaunchKernelGGL(k1_partial, dim3(BB * NCH), dim3(256), 0, stream, k, v, pref, kap, nu);
  hipLaunchKernelGGL(k2_prefix, dim3(BB * 8192 / 256), dim3(256), 0, stream, pref);
  hipLaunchKernelGGL(k3_gemm, dim3(BB * NCH), dim3(256), 0, stream, k, v, pref, kap, nu, uu, ww);
  hipLaunchKernelGGL(k4_out, dim3(BB), dim3(256), 0, stream, uu, ww, nu, out);
}